// Round 10
// baseline (87.861 us; speedup 1.0000x reference)
//
#include <hip/hip_runtime.h>
#include <hip/hip_bf16.h>

#define N_NODES 256
#define BATCH   1024
#define ROWB    528   // LDS row stride in bytes: 132 dwords = 4 banks mod 32
                      // -> column-of-rows b128 reads are <=2-way (free, m136),
                      // and all LDS addrs are base + compile-time constant.

typedef __attribute__((ext_vector_type(8))) short bf16x8;
typedef __attribute__((ext_vector_type(4))) float f32x4;

__device__ __forceinline__ float ftanh(float x) {
    // tanh(x) = 1 - 2/(exp2(x*2*log2e)+1); exp2+rcp saturate correctly
    float e = __builtin_amdgcn_exp2f(x * 2.8853900817779268f);
    float r = __builtin_amdgcn_rcpf(e + 1.0f);
    return fmaf(-2.0f, r, 1.0f);
}

__device__ __forceinline__ unsigned short f2bf(float f) {
    unsigned u = __float_as_uint(f);
    return (unsigned short)((u + 0x7fffu + ((u >> 16) & 1u)) >> 16);
}

__device__ __forceinline__ unsigned pack_bf2(float a, float b) {
    union { __hip_bfloat162 h; unsigned u; } cvt;
    cvt.h = __float22bfloat162_rn(make_float2(a, b));
    return cvt.u;
}

// DPP row_shr:N reduce (VALU pipe). After shr 8,4,2,1 the 16-lane sum is in
// lane 15 of each DPP row (round-6 post-mortem: NOT lane 0).
template <int CTRL>
__device__ __forceinline__ float dpp_add(float s) {
    int t = __builtin_amdgcn_update_dpp(0, __float_as_int(s), CTRL, 0xf, 0xf, true);
    return s + __int_as_float(t);
}

// ---------------- P1: Z0 = x @ W0^T (fp32) + prep (transposes, bf16 W1) ----
__global__ void z0_prep(const float* __restrict__ x, const float* __restrict__ W0,
                        const float* __restrict__ W1, float* __restrict__ Z0,
                        float* __restrict__ xT, float* __restrict__ W0col,
                        unsigned short* __restrict__ W1bf) {
    __shared__ float xs[32][36];
    __shared__ float ws[32][36];
    int t = threadIdx.x;

    int gb = (blockIdx.y * 32 + blockIdx.x) * 256 + t;
    {
        int i = gb >> 8, m = gb & 255;
        W0col[gb] = W0[m * 256 + i];
        W1bf[gb]  = f2bf(W1[gb]);
    }
#pragma unroll
    for (int r = 0; r < 4; ++r) {
        int id = r * 65536 + gb;
        int i = id >> 10, b = id & 1023;
        xT[id] = x[b * 256 + i];
    }

    int b0 = blockIdx.x * 32, m0 = blockIdx.y * 32;
    int lr = t >> 3, lc = (t & 7) << 2;
    int tr = (t >> 4) << 1, tc = (t & 15) << 1;
    float acc00 = 0.f, acc01 = 0.f, acc10 = 0.f, acc11 = 0.f;
    for (int k0 = 0; k0 < 256; k0 += 32) {
        *(float4*)&xs[lr][lc] = *(const float4*)&x[(b0 + lr) * 256 + k0 + lc];
        *(float4*)&ws[lr][lc] = *(const float4*)&W0[(m0 + lr) * 256 + k0 + lc];
        __syncthreads();
#pragma unroll
        for (int k = 0; k < 32; ++k) {
            float a0 = xs[tr][k], a1 = xs[tr + 1][k];
            float w0v = ws[tc][k], w1v = ws[tc + 1][k];
            acc00 = fmaf(a0, w0v, acc00);
            acc01 = fmaf(a0, w1v, acc01);
            acc10 = fmaf(a1, w0v, acc10);
            acc11 = fmaf(a1, w1v, acc11);
        }
        __syncthreads();
    }
    Z0[(b0 + tr) * 256 + m0 + tc]         = acc00;
    Z0[(b0 + tr) * 256 + m0 + tc + 1]     = acc01;
    Z0[(b0 + tr + 1) * 256 + m0 + tc]     = acc10;
    Z0[(b0 + tr + 1) * 256 + m0 + tc + 1] = acc11;
}

// ---------------- F: fused per-(node i, batch-tile) kernel ----------------
// R2 structure (4-wave/256-thread blocks, best measured) + padded LDS so
// every ds_read/ds_write is base + immediate offset (no per-access XOR math).
__launch_bounds__(256, 4)
__global__ void fused(const float* __restrict__ Z0, const float* __restrict__ xT,
                      const float* __restrict__ W0col,
                      const unsigned short* __restrict__ W1bf,
                      const float* __restrict__ W2, float* __restrict__ out) {
    __shared__ __align__(16) unsigned char h0s[64 * ROWB];  // 33 KiB padded
    __shared__ float wavepart[4 * 64];                       // 1 KiB
    const int t  = threadIdx.x;
    const int r0 = blockIdx.x * 64;   // batch tile base
    const int i  = blockIdx.y;        // node index

    const int wave = t >> 6, lane = t & 63;
    const int lr = lane & 15, lh = lane >> 4;

    // W2 values for this lane's 4 output columns (hide latency under phase 0)
    float w2v[4];
#pragma unroll
    for (int nt = 0; nt < 4; ++nt)
        w2v[nt] = W2[i * 256 + wave * 64 + nt * 16 + lr];

    // ---- phase 0: h0 = tanh(Z0 - x[:,i] (x) W0[:,i]) -> LDS (bf16, padded)
    {
        const int rowgrp = t >> 5, chunk = t & 31;   // 8 rows per thread
        const int col0 = chunk << 3;
        unsigned char* wbase = h0s + rowgrp * ROWB + chunk * 16;
        float4 w0a = *(const float4*)&W0col[i * 256 + col0];
        float4 w0b = *(const float4*)&W0col[i * 256 + col0 + 4];
        float w[8] = {w0a.x, w0a.y, w0a.z, w0a.w, w0b.x, w0b.y, w0b.z, w0b.w};
#pragma unroll
        for (int p = 0; p < 8; ++p) {
            int row = p * 8 + rowgrp;
            float xi = xT[i * 1024 + r0 + row];
            float4 za = *(const float4*)&Z0[(r0 + row) * 256 + col0];
            float4 zb = *(const float4*)&Z0[(r0 + row) * 256 + col0 + 4];
            float z[8] = {za.x, za.y, za.z, za.w, zb.x, zb.y, zb.z, zb.w};
            unsigned pk[4];
#pragma unroll
            for (int e = 0; e < 4; ++e) {
                float ha = ftanh(fmaf(-xi, w[2 * e],     z[2 * e]));
                float hb = ftanh(fmaf(-xi, w[2 * e + 1], z[2 * e + 1]));
                pk[e] = pack_bf2(ha, hb);
            }
            // byte offset p*8*ROWB is a compile-time constant -> ds_write imm
            *(uint4*)(wbase + p * 8 * ROWB) = make_uint4(pk[0], pk[1], pk[2], pk[3]);
        }
    }
    __syncthreads();

    // ---- phase 1: z1 = h0 @ W1^T via MFMA (each wave: 64 rows x 64 cols)
    f32x4 acc[4][4];
#pragma unroll
    for (int a = 0; a < 4; ++a)
#pragma unroll
        for (int b = 0; b < 4; ++b)
            acc[a][b] = (f32x4){0.f, 0.f, 0.f, 0.f};

    // Per-mt LDS base (computed once); per-ks address = base + ks*64 (imm).
    const unsigned char* abase[4];
#pragma unroll
    for (int mt = 0; mt < 4; ++mt)
        abase[mt] = h0s + (mt * 16 + lr) * ROWB + lh * 16;

    // W1 row pointers for this lane's four output features; 1-deep prefetch.
    const unsigned short* w1p[4];
#pragma unroll
    for (int nt = 0; nt < 4; ++nt)
        w1p[nt] = W1bf + (wave * 64 + nt * 16 + lr) * 256 + lh * 8;
    bf16x8 bnext[4];
#pragma unroll
    for (int nt = 0; nt < 4; ++nt)
        bnext[nt] = *(const bf16x8*)(w1p[nt]);

#pragma unroll
    for (int ks = 0; ks < 8; ++ks) {
        bf16x8 bfrag[4];
#pragma unroll
        for (int nt = 0; nt < 4; ++nt) {
            bfrag[nt] = bnext[nt];
            if (ks < 7)
                bnext[nt] = *(const bf16x8*)(w1p[nt] + (ks + 1) * 32);
        }
        bf16x8 afrag[4];
#pragma unroll
        for (int mt = 0; mt < 4; ++mt)
            afrag[mt] = *(const bf16x8*)(abase[mt] + ks * 64);  // imm offset
#pragma unroll
        for (int mt = 0; mt < 4; ++mt)
#pragma unroll
            for (int nt = 0; nt < 4; ++nt)
                acc[mt][nt] = __builtin_amdgcn_mfma_f32_16x16x32_bf16(
                    afrag[mt], bfrag[nt], acc[mt][nt], 0, 0, 0);
    }

    // ---- phase 2 (in-register): h1 = tanh(z1); dot with W2 row i;
    //      DPP reduce over 16-lane group, sum lands in lane lr==15.
    //      C/D: row = mt*16 + lh*4 + r, col = wave*64 + nt*16 + lr
#pragma unroll
    for (int mt = 0; mt < 4; ++mt) {
#pragma unroll
        for (int r = 0; r < 4; ++r) {
            float s = fmaf(ftanh(acc[mt][0][r]), w2v[0],
                           ftanh(acc[mt][1][r]) * w2v[1]);
            s = fmaf(ftanh(acc[mt][2][r]), w2v[2], s);
            s = fmaf(ftanh(acc[mt][3][r]), w2v[3], s);
            s = dpp_add<0x118>(s);   // row_shr:8
            s = dpp_add<0x114>(s);   // row_shr:4
            s = dpp_add<0x112>(s);   // row_shr:2
            s = dpp_add<0x111>(s);   // row_shr:1  -> lane 15 has the sum
            if (lr == 15)
                wavepart[wave * 64 + mt * 16 + lh * 4 + r] = s;
        }
    }
    __syncthreads();

    // ---- phase 3: sum 4 wave partials, final tanh, store column i
    if (t < 64) {
        float s = wavepart[t] + wavepart[64 + t] + wavepart[128 + t] + wavepart[192 + t];
        out[(r0 + t) * 256 + i] = ftanh(s);
    }
}

extern "C" void kernel_launch(void* const* d_in, const int* in_sizes, int n_in,
                              void* d_out, int out_size, void* d_ws, size_t ws_size,
                              hipStream_t stream) {
    const float* x  = (const float*)d_in[0];
    const float* W0 = (const float*)d_in[1];
    const float* W1 = (const float*)d_in[2];
    const float* W2 = (const float*)d_in[3];
    float* out = (float*)d_out;

    char* ws = (char*)d_ws;
    float* Z0            = (float*)ws;                               // 1 MB
    float* xT            = (float*)(ws + (1 << 20));                 // 1 MB
    float* W0col         = (float*)(ws + (2 << 20));                 // 256 KB
    unsigned short* W1bf = (unsigned short*)(ws + (2 << 20) + (256 << 10)); // 128 KB

    z0_prep<<<dim3(32, 8), 256, 0, stream>>>(x, W0, W1, Z0, xT, W0col, W1bf);
    fused<<<dim3(16, 256), 256, 0, stream>>>(Z0, xT, W0col, W1bf, W2, out);
}

// Round 11
// 87.709 us; speedup vs baseline: 1.0017x; 1.0017x over previous
//
#include <hip/hip_runtime.h>
#include <hip/hip_bf16.h>

#define N_NODES 256
#define BATCH   1024
#define ROWB    528   // LDS row stride in bytes: 132 dwords = 4 banks mod 32
                      // -> column-of-rows b128 reads are <=2-way (free, m136),
                      // and all LDS addrs are base + compile-time constant.

typedef __attribute__((ext_vector_type(8))) short bf16x8;
typedef __attribute__((ext_vector_type(4))) float f32x4;

__device__ __forceinline__ float ftanh(float x) {
    // tanh(x) = 1 - 2/(exp2(x*2*log2e)+1); exp2+rcp saturate correctly
    float e = __builtin_amdgcn_exp2f(x * 2.8853900817779268f);
    float r = __builtin_amdgcn_rcpf(e + 1.0f);
    return fmaf(-2.0f, r, 1.0f);
}

__device__ __forceinline__ unsigned short f2bf(float f) {
    unsigned u = __float_as_uint(f);
    return (unsigned short)((u + 0x7fffu + ((u >> 16) & 1u)) >> 16);
}

__device__ __forceinline__ unsigned pack_bf2(float a, float b) {
    union { __hip_bfloat162 h; unsigned u; } cvt;
    cvt.h = __float22bfloat162_rn(make_float2(a, b));
    return cvt.u;
}

// DPP row_shr:N reduce (VALU pipe). After shr 8,4,2,1 the 16-lane sum is in
// lane 15 of each DPP row (round-6 post-mortem: NOT lane 0).
template <int CTRL>
__device__ __forceinline__ float dpp_add(float s) {
    int t = __builtin_amdgcn_update_dpp(0, __float_as_int(s), CTRL, 0xf, 0xf, true);
    return s + __int_as_float(t);
}

// ---------------- P1: Z0 = x @ W0^T (fp32) + prep (transposes, bf16 W1) ----
__global__ void z0_prep(const float* __restrict__ x, const float* __restrict__ W0,
                        const float* __restrict__ W1, float* __restrict__ Z0,
                        float* __restrict__ xT, float* __restrict__ W0col,
                        unsigned short* __restrict__ W1bf) {
    __shared__ float xs[32][36];
    __shared__ float ws[32][36];
    int t = threadIdx.x;

    int gb = (blockIdx.y * 32 + blockIdx.x) * 256 + t;
    {
        int i = gb >> 8, m = gb & 255;
        W0col[gb] = W0[m * 256 + i];
        W1bf[gb]  = f2bf(W1[gb]);
    }
#pragma unroll
    for (int r = 0; r < 4; ++r) {
        int id = r * 65536 + gb;
        int i = id >> 10, b = id & 1023;
        xT[id] = x[b * 256 + i];
    }

    int b0 = blockIdx.x * 32, m0 = blockIdx.y * 32;
    int lr = t >> 3, lc = (t & 7) << 2;
    int tr = (t >> 4) << 1, tc = (t & 15) << 1;
    float acc00 = 0.f, acc01 = 0.f, acc10 = 0.f, acc11 = 0.f;
    for (int k0 = 0; k0 < 256; k0 += 32) {
        *(float4*)&xs[lr][lc] = *(const float4*)&x[(b0 + lr) * 256 + k0 + lc];
        *(float4*)&ws[lr][lc] = *(const float4*)&W0[(m0 + lr) * 256 + k0 + lc];
        __syncthreads();
#pragma unroll
        for (int k = 0; k < 32; ++k) {
            float a0 = xs[tr][k], a1 = xs[tr + 1][k];
            float w0v = ws[tc][k], w1v = ws[tc + 1][k];
            acc00 = fmaf(a0, w0v, acc00);
            acc01 = fmaf(a0, w1v, acc01);
            acc10 = fmaf(a1, w0v, acc10);
            acc11 = fmaf(a1, w1v, acc11);
        }
        __syncthreads();
    }
    Z0[(b0 + tr) * 256 + m0 + tc]         = acc00;
    Z0[(b0 + tr) * 256 + m0 + tc + 1]     = acc01;
    Z0[(b0 + tr + 1) * 256 + m0 + tc]     = acc10;
    Z0[(b0 + tr + 1) * 256 + m0 + tc + 1] = acc11;
}

// ---------------- F: fused per-(node i, batch-tile) kernel ----------------
// R2 structure (4-wave/256-thread blocks, best measured) + padded LDS so
// every ds_read/ds_write is base + immediate offset (no per-access XOR math).
__launch_bounds__(256, 4)
__global__ void fused(const float* __restrict__ Z0, const float* __restrict__ xT,
                      const float* __restrict__ W0col,
                      const unsigned short* __restrict__ W1bf,
                      const float* __restrict__ W2, float* __restrict__ out) {
    __shared__ __align__(16) unsigned char h0s[64 * ROWB];  // 33 KiB padded
    __shared__ float wavepart[4 * 64];                       // 1 KiB
    const int t  = threadIdx.x;
    const int r0 = blockIdx.x * 64;   // batch tile base
    const int i  = blockIdx.y;        // node index

    const int wave = t >> 6, lane = t & 63;
    const int lr = lane & 15, lh = lane >> 4;

    // W2 values for this lane's 4 output columns (hide latency under phase 0)
    float w2v[4];
#pragma unroll
    for (int nt = 0; nt < 4; ++nt)
        w2v[nt] = W2[i * 256 + wave * 64 + nt * 16 + lr];

    // ---- phase 0: h0 = tanh(Z0 - x[:,i] (x) W0[:,i]) -> LDS (bf16, padded)
    {
        const int rowgrp = t >> 5, chunk = t & 31;   // 8 rows per thread
        const int col0 = chunk << 3;
        unsigned char* wbase = h0s + rowgrp * ROWB + chunk * 16;
        float4 w0a = *(const float4*)&W0col[i * 256 + col0];
        float4 w0b = *(const float4*)&W0col[i * 256 + col0 + 4];
        float w[8] = {w0a.x, w0a.y, w0a.z, w0a.w, w0b.x, w0b.y, w0b.z, w0b.w};
#pragma unroll
        for (int p = 0; p < 8; ++p) {
            int row = p * 8 + rowgrp;
            float xi = xT[i * 1024 + r0 + row];
            float4 za = *(const float4*)&Z0[(r0 + row) * 256 + col0];
            float4 zb = *(const float4*)&Z0[(r0 + row) * 256 + col0 + 4];
            float z[8] = {za.x, za.y, za.z, za.w, zb.x, zb.y, zb.z, zb.w};
            unsigned pk[4];
#pragma unroll
            for (int e = 0; e < 4; ++e) {
                float ha = ftanh(fmaf(-xi, w[2 * e],     z[2 * e]));
                float hb = ftanh(fmaf(-xi, w[2 * e + 1], z[2 * e + 1]));
                pk[e] = pack_bf2(ha, hb);
            }
            // byte offset p*8*ROWB is a compile-time constant -> ds_write imm
            *(uint4*)(wbase + p * 8 * ROWB) = make_uint4(pk[0], pk[1], pk[2], pk[3]);
        }
    }
    __syncthreads();

    // ---- phase 1: z1 = h0 @ W1^T via MFMA (each wave: 64 rows x 64 cols)
    f32x4 acc[4][4];
#pragma unroll
    for (int a = 0; a < 4; ++a)
#pragma unroll
        for (int b = 0; b < 4; ++b)
            acc[a][b] = (f32x4){0.f, 0.f, 0.f, 0.f};

    // Per-mt LDS base (computed once); per-ks address = base + ks*64 (imm).
    const unsigned char* abase[4];
#pragma unroll
    for (int mt = 0; mt < 4; ++mt)
        abase[mt] = h0s + (mt * 16 + lr) * ROWB + lh * 16;

    // W1 row pointers for this lane's four output features; 1-deep prefetch.
    const unsigned short* w1p[4];
#pragma unroll
    for (int nt = 0; nt < 4; ++nt)
        w1p[nt] = W1bf + (wave * 64 + nt * 16 + lr) * 256 + lh * 8;
    bf16x8 bnext[4];
#pragma unroll
    for (int nt = 0; nt < 4; ++nt)
        bnext[nt] = *(const bf16x8*)(w1p[nt]);

#pragma unroll
    for (int ks = 0; ks < 8; ++ks) {
        bf16x8 bfrag[4];
#pragma unroll
        for (int nt = 0; nt < 4; ++nt) {
            bfrag[nt] = bnext[nt];
            if (ks < 7)
                bnext[nt] = *(const bf16x8*)(w1p[nt] + (ks + 1) * 32);
        }
        bf16x8 afrag[4];
#pragma unroll
        for (int mt = 0; mt < 4; ++mt)
            afrag[mt] = *(const bf16x8*)(abase[mt] + ks * 64);  // imm offset
#pragma unroll
        for (int mt = 0; mt < 4; ++mt)
#pragma unroll
            for (int nt = 0; nt < 4; ++nt)
                acc[mt][nt] = __builtin_amdgcn_mfma_f32_16x16x32_bf16(
                    afrag[mt], bfrag[nt], acc[mt][nt], 0, 0, 0);
    }

    // ---- phase 2 (in-register): h1 = tanh(z1); dot with W2 row i;
    //      DPP reduce over 16-lane group, sum lands in lane lr==15.
    //      C/D: row = mt*16 + lh*4 + r, col = wave*64 + nt*16 + lr
#pragma unroll
    for (int mt = 0; mt < 4; ++mt) {
#pragma unroll
        for (int r = 0; r < 4; ++r) {
            float s = fmaf(ftanh(acc[mt][0][r]), w2v[0],
                           ftanh(acc[mt][1][r]) * w2v[1]);
            s = fmaf(ftanh(acc[mt][2][r]), w2v[2], s);
            s = fmaf(ftanh(acc[mt][3][r]), w2v[3], s);
            s = dpp_add<0x118>(s);   // row_shr:8
            s = dpp_add<0x114>(s);   // row_shr:4
            s = dpp_add<0x112>(s);   // row_shr:2
            s = dpp_add<0x111>(s);   // row_shr:1  -> lane 15 has the sum
            if (lr == 15)
                wavepart[wave * 64 + mt * 16 + lh * 4 + r] = s;
        }
    }
    __syncthreads();

    // ---- phase 3: sum 4 wave partials, final tanh, store column i
    if (t < 64) {
        float s = wavepart[t] + wavepart[64 + t] + wavepart[128 + t] + wavepart[192 + t];
        out[(r0 + t) * 256 + i] = ftanh(s);
    }
}

extern "C" void kernel_launch(void* const* d_in, const int* in_sizes, int n_in,
                              void* d_out, int out_size, void* d_ws, size_t ws_size,
                              hipStream_t stream) {
    const float* x  = (const float*)d_in[0];
    const float* W0 = (const float*)d_in[1];
    const float* W1 = (const float*)d_in[2];
    const float* W2 = (const float*)d_in[3];
    float* out = (float*)d_out;

    char* ws = (char*)d_ws;
    float* Z0            = (float*)ws;                               // 1 MB
    float* xT            = (float*)(ws + (1 << 20));                 // 1 MB
    float* W0col         = (float*)(ws + (2 << 20));                 // 256 KB
    unsigned short* W1bf = (unsigned short*)(ws + (2 << 20) + (256 << 10)); // 128 KB

    z0_prep<<<dim3(32, 8), 256, 0, stream>>>(x, W0, W1, Z0, xT, W0col, W1bf);
    fused<<<dim3(16, 256), 256, 0, stream>>>(Z0, xT, W0col, W1bf, W2, out);
}